// Round 6
// baseline (552.259 us; speedup 1.0000x reference)
//
#include <hip/hip_runtime.h>
#include <math.h>

#define NTOK 16384
#define KD   2048
#define NE   256
#define NCHUNK 128            // KD / 16
#define CHUNK_DW 4096         // NE * 16 dwords per 16-K chunk image
#define TM 16                 // tokens per block
#define SL 257                // Ls row stride (floats)

// ---- kernel 0: pre-transform W into chunked, lane-linear slab image.
// Slab s = (e>>5)*2 + ((e>>4)&1)  (j-major, wave-half minor), slot lane = (e&15)*4 + l.
// Bt[c][s*256 + lane*4 + q] = W[e][16c + 4q + l]
// => gate wave reads (fixed j) are 64 consecutive 16B slots: conflict-free.
__global__ __launch_bounds__(256) void transform_kernel(
    const float* __restrict__ wgt, float* __restrict__ Bt)
{
    const int c    = blockIdx.x >> 2;
    const int qt   = blockIdx.x & 3;
    const int slot = qt * 256 + threadIdx.x;      // 0..1023
    const int s    = slot >> 6;                   // slab 0..15
    const int lane = slot & 63;
    const int em   = lane >> 2;
    const int l    = lane & 3;
    const int e    = (s >> 1) * 32 + (s & 1) * 16 + em;
    const float* src = wgt + (size_t)e * KD + 16 * c + l;
    float4 v = make_float4(src[0], src[4], src[8], src[12]);   // q = 0..3
    *(float4*)(Bt + (size_t)c * CHUNK_DW + slot * 4) = v;
}

typedef __attribute__((address_space(1))) const void GV;
typedef __attribute__((address_space(3))) void LV;
__device__ __forceinline__ void gld_lds16(const float* g, float* l) {
    __builtin_amdgcn_global_load_lds((GV*)g, (LV*)l, 16, 0, 0);
}

// Bit-exact replication of numpy npyv(SSE3,no-FMA) einsum:
//   lane l sums k ≡ l (mod 4); per 16-block: s = p0+(p1+(p2+(p3+s)));
//   final (s0+s1)+(s2+s3).  Lane-chains split across thread-quads.
__global__ __launch_bounds__(256) void gate_kernel(
    const float* __restrict__ hid, const float* __restrict__ Bt,
    float* __restrict__ out, float* __restrict__ cnt, float* __restrict__ prb)
{
    __shared__ union { float bs[2][CHUNK_DW]; float ls[TM][SL]; } sh;
    __shared__ float As[2][TM][16];
    __shared__ float maxS[TM], sumS[TM], invS[TM];

    const int tid  = threadIdx.x;
    const int l    = tid & 3;
    const int eg   = (tid >> 2) & 31;      // experts eg, eg+32, ..., eg+224
    const int tg   = tid >> 7;             // token group 0/1 (8 tokens each)
    const int t0   = blockIdx.x * TM;
    const int lane = tid & 63;
    const int w    = tid >> 6;
    const int h    = w & 1;                // wave-half: eg<16 -> 0, eg>=16 -> 1

    float acc[8][8];
#pragma unroll
    for (int i = 0; i < 8; ++i)
#pragma unroll
        for (int j = 0; j < 8; ++j) acc[i][j] = 0.f;

    // ---- A staging (16 lanes per wave: one float4 = fixed q, l=0..3) ----
    const bool aact = (lane < 16);
    const int  at   = w * 4 + (lane >> 2);   // token 0..15
    const int  aq   = lane & 3;
    float av[4];

    auto stageA_load = [&](int c) {
        if (aact)
            *(float4*)av = *(const float4*)(hid + (size_t)(t0 + at) * KD + 16 * c + 4 * aq);
    };
    auto stageA_write = [&](int buf) {
        if (aact) {
#pragma unroll
            for (int ll = 0; ll < 4; ++ll)
                As[buf][at][ll * 4 + aq] = av[ll];
        }
    };
    auto stageB = [&](int c, int buf) {
        const float* src = Bt + (size_t)c * CHUNK_DW + tid * 4;
        float* dst = &sh.bs[buf][tid * 4];
#pragma unroll
        for (int s = 0; s < 4; ++s)
            gld_lds16(src + s * 1024, dst + s * 1024);
    };

    stageA_load(0);
    stageB(0, 0);
    stageA_write(0);
    int cur = 0;

#pragma unroll 1
    for (int c = 0; c < NCHUNK; ++c) {
        __syncthreads();                       // cur buffers ready; nxt free
        const int nxt = cur ^ 1;
        if (c + 1 < NCHUNK) { stageA_load(c + 1); stageB(c + 1, nxt); }

        float4 a[8];
#pragma unroll
        for (int tt = 0; tt < 8; ++tt)
            a[tt] = *(const float4*)&As[cur][tg * 8 + tt][l * 4];
#pragma unroll
        for (int j = 0; j < 8; ++j) {
            const float4 b = *(const float4*)&sh.bs[cur][((j * 2 + h) << 8) + (lane << 2)];
#pragma unroll
            for (int tt = 0; tt < 8; ++tt) {
                float s = acc[tt][j];
                s = __fadd_rn(__fmul_rn(a[tt].w, b.w), s);   // q=3
                s = __fadd_rn(__fmul_rn(a[tt].z, b.z), s);   // q=2
                s = __fadd_rn(__fmul_rn(a[tt].y, b.y), s);   // q=1
                s = __fadd_rn(__fmul_rn(a[tt].x, b.x), s);   // q=0
                acc[tt][j] = s;
            }
        }
        if (c + 1 < NCHUNK) stageA_write(nxt);
        cur = nxt;
    }

    // ---- combine lane-chains: (s0+s1)+(s2+s3), bitwise-commutative adds ----
    __syncthreads();                           // all waves done reading bs
#pragma unroll
    for (int tt = 0; tt < 8; ++tt)
#pragma unroll
        for (int j = 0; j < 8; ++j) {
            float s = acc[tt][j];
            s = __fadd_rn(s, __shfl_xor(s, 1));
            s = __fadd_rn(s, __shfl_xor(s, 2));
            if (l == 0) sh.ls[tg * 8 + tt][eg + 32 * j] = s;
        }
    if (tid < TM) sumS[tid] = 0.f;
    __syncthreads();

    // ---- per-token top-k (threads 0..15), fp32 bit-exact ----
    if (tid < TM) {
        const float* lr = &sh.ls[tid][0];
        float tv[8]; int ti[8];
#pragma unroll
        for (int j = 0; j < 8; ++j) { tv[j] = -1e30f; ti[j] = 0; }
        float rowmax = -1e30f;

        auto ins8 = [&](float v, int idx) {
#pragma unroll
            for (int p = 0; p < 8; ++p) {
                if (v > tv[p]) {
#pragma unroll
                    for (int q = 7; q > p; --q) { tv[q] = tv[q - 1]; ti[q] = ti[q - 1]; }
                    tv[p] = v; ti[p] = idx;
                    break;
                }
            }
        };

#pragma unroll 1
        for (int g = 0; g < 8; ++g) {
            float v0 = -1e30f, v1 = -1e30f, v2 = -1e30f, v3 = -1e30f;
            int   i0 = 0, i1 = 0, i2 = 0, i3 = 0;
            for (int j = 0; j < 32; ++j) {
                const float v = lr[g * 32 + j];
                if (v > v0)      { v3=v2;i3=i2; v2=v1;i2=i1; v1=v0;i1=i0; v0=v;i0=j; }
                else if (v > v1) { v3=v2;i3=i2; v2=v1;i2=i1; v1=v;i1=j; }
                else if (v > v2) { v3=v2;i3=i2; v2=v;i2=j; }
                else if (v > v3) { v3=v;i3=j; }
            }
            rowmax = fmaxf(rowmax, v0);
            ins8(v0, g * 32 + i0);
            ins8(v1, g * 32 + i1);
            ins8(v2, g * 32 + i2);
            ins8(v3, g * 32 + i3);
        }

        const float s01 = __fadd_rn(tv[0], tv[1]);
        const float s23 = __fadd_rn(tv[2], tv[3]);
        const float s45 = __fadd_rn(tv[4], tv[5]);
        const float s67 = __fadd_rn(tv[6], tv[7]);
        float s = __fadd_rn(__fadd_rn(s01, s23), __fadd_rn(s45, s67));
        s = __fadd_rn(s, 1e-20f);

        const size_t tg2 = (size_t)(t0 + tid);
#pragma unroll
        for (int j = 0; j < 8; ++j) {
            out[tg2 * 8 + j]                    = (float)ti[j];
            out[(size_t)NTOK * 8 + tg2 * 8 + j] = __fdiv_rn(tv[j], s);
            atomicAdd(&cnt[ti[j]], 1.0f);
        }
        maxS[tid] = rowmax;
    }
    __syncthreads();

    // ---- per-token softmax denominator (16 threads per token) ----
    {
        const int t  = tid >> 4;
        const int c0 = (tid & 15) * 16;
        const float m = maxS[t];
        float part = 0.f;
#pragma unroll
        for (int j = 0; j < 16; ++j) part += __expf(sh.ls[t][c0 + j] - m);
        atomicAdd(&sumS[t], part);
    }
    __syncthreads();
    if (tid < TM) invS[tid] = 1.0f / sumS[tid];
    __syncthreads();

    // ---- per-expert softmax-prob partial over block tokens ----
    {
        float p = 0.f;
#pragma unroll
        for (int n = 0; n < TM; ++n) p += __expf(sh.ls[n][tid] - maxS[n]) * invS[n];
        atomicAdd(&prb[tid], p);
    }
}

__global__ void aux_kernel(const float* __restrict__ cnt,
                           const float* __restrict__ prb,
                           float* __restrict__ out)
{
    const int tid = threadIdx.x;
    float v = cnt[tid] * prb[tid];
#pragma unroll
    for (int off = 32; off; off >>= 1) v += __shfl_down(v, off, 64);
    __shared__ float ps[4];
    if ((tid & 63) == 0) ps[tid >> 6] = v;
    __syncthreads();
    if (tid == 0) {
        const float tot = ps[0] + ps[1] + ps[2] + ps[3];
        out[(size_t)NTOK * 8 * 2] = tot * (0.001f / (131072.0f * 16384.0f));
    }
}

extern "C" void kernel_launch(void* const* d_in, const int* in_sizes, int n_in,
                              void* d_out, int out_size, void* d_ws, size_t ws_size,
                              hipStream_t stream)
{
    (void)in_sizes; (void)n_in; (void)out_size; (void)ws_size;
    const float* hid = (const float*)d_in[0];
    const float* wgt = (const float*)d_in[1];
    float* out = (float*)d_out;
    float* cnt = (float*)d_ws;             // 256 f
    float* prb = cnt + NE;                 // 256 f
    float* Bt  = prb + NE;                 // 2 MB image (16B-aligned: 2048B offset)

    hipMemsetAsync(d_ws, 0, 2 * NE * sizeof(float), stream);
    transform_kernel<<<512, 256, 0, stream>>>(wgt, Bt);
    gate_kernel<<<NTOK / TM, 256, 0, stream>>>(hid, Bt, out, cnt, prb);
    aux_kernel<<<1, 256, 0, stream>>>(cnt, prb, out);
}

// Round 7
// 534.659 us; speedup vs baseline: 1.0329x; 1.0329x over previous
//
#include <hip/hip_runtime.h>
#include <math.h>

#define NTOK 16384
#define KD   2048
#define NE   256
#define NCHUNK 128            // KD / 16
#define CHUNK_DW 4096         // NE * 16 dwords per 16-K chunk image
#define TM 32                 // tokens per block
#define SL 257                // Ls row stride (floats)

typedef float f32x2 __attribute__((ext_vector_type(2)));

// d = a * {b.lo, b.lo}  (broadcast low half of b)
__device__ __forceinline__ f32x2 pk_mul_lo(f32x2 a, f32x2 b) {
    f32x2 d;
    asm("v_pk_mul_f32 %0, %1, %2 op_sel:[0,0] op_sel_hi:[1,0]"
        : "=v"(d) : "v"(a), "v"(b));
    return d;
}
// d = a * {b.hi, b.hi}  (broadcast high half of b)
__device__ __forceinline__ f32x2 pk_mul_hi(f32x2 a, f32x2 b) {
    f32x2 d;
    asm("v_pk_mul_f32 %0, %1, %2 op_sel:[0,1] op_sel_hi:[1,1]"
        : "=v"(d) : "v"(a), "v"(b));
    return d;
}
__device__ __forceinline__ f32x2 pk_add(f32x2 a, f32x2 b) {
    f32x2 d;
    asm("v_pk_add_f32 %0, %1, %2" : "=v"(d) : "v"(a), "v"(b));
    return d;
}

// ---- kernel 0: pre-transform W into chunked, lane-linear slab image.
// Slab s = (e>>5)*2 + ((e>>4)&1), slot lane = (e&15)*4 + l.
// Bt[c][s*256 + lane*4 + q] = W[e][16c + 4q + l]   (identical to round 6)
__global__ __launch_bounds__(256) void transform_kernel(
    const float* __restrict__ wgt, float* __restrict__ Bt)
{
    const int c    = blockIdx.x >> 2;
    const int qt   = blockIdx.x & 3;
    const int slot = qt * 256 + threadIdx.x;      // 0..1023
    const int s    = slot >> 6;                   // slab 0..15
    const int lane = slot & 63;
    const int em   = lane >> 2;
    const int l    = lane & 3;
    const int e    = (s >> 1) * 32 + (s & 1) * 16 + em;
    const float* src = wgt + (size_t)e * KD + 16 * c + l;
    float4 v = make_float4(src[0], src[4], src[8], src[12]);   // q = 0..3
    *(float4*)(Bt + (size_t)c * CHUNK_DW + slot * 4) = v;
}

typedef __attribute__((address_space(1))) const void GV;
typedef __attribute__((address_space(3))) void LV;
__device__ __forceinline__ void gld_lds16(const float* g, float* l) {
    __builtin_amdgcn_global_load_lds((GV*)g, (LV*)l, 16, 0, 0);
}

// Bit-exact numpy npyv(SSE3,no-FMA) einsum; lane-chains split across thread
// quads (l = tid&3); token-PAIRS packed into v_pk_{mul,add}_f32 chains.
__global__ __launch_bounds__(512, 4) void gate_kernel(
    const float* __restrict__ hid, const float* __restrict__ Bt,
    float* __restrict__ out, float* __restrict__ cnt, float* __restrict__ prb)
{
    __shared__ union { float bs[2][CHUNK_DW]; float ls[TM][SL]; } sh;
    __shared__ float As2[2][4][132];   // [buf][l][tp*8 + q*2 + par], stride 132
    __shared__ float maxS[TM], sumS[TM], invS[TM];

    const int tid  = threadIdx.x;
    const int l    = tid & 3;
    const int eg   = (tid >> 2) & 31;      // experts eg, eg+32, ..., eg+224
    const int tg   = tid >> 7;             // token group 0..3 (8 tokens each)
    const int t0   = blockIdx.x * TM;
    const int lane = tid & 63;
    const int w    = tid >> 6;
    const int h    = w & 1;                // expert half within slab pair

    f32x2 acc2[4][8];                      // [token-pair][j]
#pragma unroll
    for (int i = 0; i < 4; ++i)
#pragma unroll
        for (int j = 0; j < 8; ++j) acc2[i][j] = (f32x2){0.f, 0.f};

    // ---- A staging: 16 lanes/wave × 8 waves cover (tok 0..31) × (q 0..3) ----
    const bool aact = (lane < 16);
    const int  at   = w * 4 + (lane >> 2);   // token 0..31
    const int  aq   = lane & 3;              // q
    float av[4];                             // l = 0..3

    auto stageA_load = [&](int c) {
        if (aact)
            *(float4*)av = *(const float4*)(hid + (size_t)(t0 + at) * KD + 16 * c + 4 * aq);
    };
    auto stageA_write = [&](int buf) {
        if (aact) {
            const int base = (at >> 1) * 8 + aq * 2 + (at & 1);
#pragma unroll
            for (int ll = 0; ll < 4; ++ll)
                As2[buf][ll][base] = av[ll];
        }
    };
    auto stageB = [&](int c, int buf) {
        const float* src = Bt + (size_t)c * CHUNK_DW + tid * 4;
        float* dst = &sh.bs[buf][tid * 4];
        gld_lds16(src, dst);
        gld_lds16(src + 2048, dst + 2048);
    };

    stageA_load(0);
    stageB(0, 0);
    stageA_write(0);
    int cur = 0;

#pragma unroll 1
    for (int c = 0; c < NCHUNK; ++c) {
        __syncthreads();                       // cur buffers ready; nxt free
        const int nxt = cur ^ 1;
        if (c + 1 < NCHUNK) { stageA_load(c + 1); stageB(c + 1, nxt); }

        // A fragments: per token-pair, float4 = {q0-pair, q1-pair} and {q2,q3}
        float4 ar0[4], ar1[4];
#pragma unroll
        for (int tp = 0; tp < 4; ++tp) {
            const float* ap = &As2[cur][l][(tg * 4 + tp) * 8];
            ar0[tp] = *(const float4*)(ap);
            ar1[tp] = *(const float4*)(ap + 4);
        }
#pragma unroll
        for (int j = 0; j < 8; ++j) {
            const float4 b = *(const float4*)&sh.bs[cur][((j * 2 + h) << 8) + (lane << 2)];
            const f32x2 b01 = (f32x2){b.x, b.y};   // {q0, q1}
            const f32x2 b23 = (f32x2){b.z, b.w};   // {q2, q3}
#pragma unroll
            for (int tp = 0; tp < 4; ++tp) {
                const f32x2 aQ0 = (f32x2){ar0[tp].x, ar0[tp].y};
                const f32x2 aQ1 = (f32x2){ar0[tp].z, ar0[tp].w};
                const f32x2 aQ2 = (f32x2){ar1[tp].x, ar1[tp].y};
                const f32x2 aQ3 = (f32x2){ar1[tp].z, ar1[tp].w};
                f32x2 s = acc2[tp][j];
                s = pk_add(pk_mul_hi(aQ3, b23), s);   // q=3
                s = pk_add(pk_mul_lo(aQ2, b23), s);   // q=2
                s = pk_add(pk_mul_hi(aQ1, b01), s);   // q=1
                s = pk_add(pk_mul_lo(aQ0, b01), s);   // q=0
                acc2[tp][j] = s;
            }
        }
        if (c + 1 < NCHUNK) stageA_write(nxt);
        cur = nxt;
    }

    // ---- combine lane-chains: (s0+s1)+(s2+s3) per component ----
    __syncthreads();                           // all waves done reading bs
#pragma unroll
    for (int tp = 0; tp < 4; ++tp)
#pragma unroll
        for (int j = 0; j < 8; ++j) {
            float sx = acc2[tp][j].x, sy = acc2[tp][j].y;
            sx = __fadd_rn(sx, __shfl_xor(sx, 1));
            sx = __fadd_rn(sx, __shfl_xor(sx, 2));
            sy = __fadd_rn(sy, __shfl_xor(sy, 1));
            sy = __fadd_rn(sy, __shfl_xor(sy, 2));
            if (l == 0) {
                sh.ls[tg * 8 + 2 * tp][eg + 32 * j]     = sx;
                sh.ls[tg * 8 + 2 * tp + 1][eg + 32 * j] = sy;
            }
        }
    if (tid < TM) sumS[tid] = 0.f;
    __syncthreads();

    // ---- per-token top-k (threads 0..31), fp32 bit-exact ----
    if (tid < TM) {
        const float* lr = &sh.ls[tid][0];
        float tv[8]; int ti[8];
#pragma unroll
        for (int j = 0; j < 8; ++j) { tv[j] = -1e30f; ti[j] = 0; }
        float rowmax = -1e30f;

        auto ins8 = [&](float v, int idx) {
#pragma unroll
            for (int p = 0; p < 8; ++p) {
                if (v > tv[p]) {
#pragma unroll
                    for (int q = 7; q > p; --q) { tv[q] = tv[q - 1]; ti[q] = ti[q - 1]; }
                    tv[p] = v; ti[p] = idx;
                    break;
                }
            }
        };

#pragma unroll 1
        for (int g = 0; g < 8; ++g) {
            float v0 = -1e30f, v1 = -1e30f, v2 = -1e30f, v3 = -1e30f;
            int   i0 = 0, i1 = 0, i2 = 0, i3 = 0;
            for (int j = 0; j < 32; ++j) {
                const float v = lr[g * 32 + j];
                if (v > v0)      { v3=v2;i3=i2; v2=v1;i2=i1; v1=v0;i1=i0; v0=v;i0=j; }
                else if (v > v1) { v3=v2;i3=i2; v2=v1;i2=i1; v1=v;i1=j; }
                else if (v > v2) { v3=v2;i3=i2; v2=v;i2=j; }
                else if (v > v3) { v3=v;i3=j; }
            }
            rowmax = fmaxf(rowmax, v0);
            ins8(v0, g * 32 + i0);
            ins8(v1, g * 32 + i1);
            ins8(v2, g * 32 + i2);
            ins8(v3, g * 32 + i3);
        }

        const float s01 = __fadd_rn(tv[0], tv[1]);
        const float s23 = __fadd_rn(tv[2], tv[3]);
        const float s45 = __fadd_rn(tv[4], tv[5]);
        const float s67 = __fadd_rn(tv[6], tv[7]);
        float s = __fadd_rn(__fadd_rn(s01, s23), __fadd_rn(s45, s67));
        s = __fadd_rn(s, 1e-20f);

        const size_t tg2 = (size_t)(t0 + tid);
#pragma unroll
        for (int j = 0; j < 8; ++j) {
            out[tg2 * 8 + j]                    = (float)ti[j];
            out[(size_t)NTOK * 8 + tg2 * 8 + j] = __fdiv_rn(tv[j], s);
            atomicAdd(&cnt[ti[j]], 1.0f);
        }
        maxS[tid] = rowmax;
    }
    __syncthreads();

    // ---- per-token softmax denominator (16 threads per token, 32 tokens) ----
    {
        const int t  = tid >> 4;
        const int c0 = (tid & 15) * 16;
        const float m = maxS[t];
        float part = 0.f;
#pragma unroll
        for (int j = 0; j < 16; ++j) part += __expf(sh.ls[t][c0 + j] - m);
        atomicAdd(&sumS[t], part);
    }
    __syncthreads();
    if (tid < TM) invS[tid] = 1.0f / sumS[tid];
    __syncthreads();

    // ---- per-expert softmax-prob partial over block tokens ----
    if (tid < NE) {
        float p = 0.f;
#pragma unroll
        for (int n = 0; n < TM; ++n) p += __expf(sh.ls[n][tid] - maxS[n]) * invS[n];
        atomicAdd(&prb[tid], p);
    }
}

__global__ void aux_kernel(const float* __restrict__ cnt,
                           const float* __restrict__ prb,
                           float* __restrict__ out)
{
    const int tid = threadIdx.x;
    float v = cnt[tid] * prb[tid];
#pragma unroll
    for (int off = 32; off; off >>= 1) v += __shfl_down(v, off, 64);
    __shared__ float ps[4];
    if ((tid & 63) == 0) ps[tid >> 6] = v;
    __syncthreads();
    if (tid == 0) {
        const float tot = ps[0] + ps[1] + ps[2] + ps[3];
        out[(size_t)NTOK * 8 * 2] = tot * (0.001f / (131072.0f * 16384.0f));
    }
}

extern "C" void kernel_launch(void* const* d_in, const int* in_sizes, int n_in,
                              void* d_out, int out_size, void* d_ws, size_t ws_size,
                              hipStream_t stream)
{
    (void)in_sizes; (void)n_in; (void)out_size; (void)ws_size;
    const float* hid = (const float*)d_in[0];
    const float* wgt = (const float*)d_in[1];
    float* out = (float*)d_out;
    float* cnt = (float*)d_ws;             // 256 f
    float* prb = cnt + NE;                 // 256 f
    float* Bt  = prb + NE;                 // 2 MB image (16B-aligned offset)

    hipMemsetAsync(d_ws, 0, 2 * NE * sizeof(float), stream);
    transform_kernel<<<512, 256, 0, stream>>>(wgt, Bt);
    gate_kernel<<<NTOK / TM, 512, 0, stream>>>(hid, Bt, out, cnt, prb);
    aux_kernel<<<1, 256, 0, stream>>>(cnt, prb, out);
}

// Round 8
// 493.645 us; speedup vs baseline: 1.1187x; 1.0831x over previous
//
#include <hip/hip_runtime.h>
#include <math.h>

#define NTOK 16384
#define KD   2048
#define NE   256
#define NCHUNK16 128          // KD / 16 (transform granularity)
#define NCHUNK   64           // KD / 32 (gate loop granularity)
#define CHUNK_DW 4096         // NE * 16 dwords per 16-K chunk image
#define TM 32                 // tokens per block
#define SL 257                // Ls row stride (floats)
#define SA 260                // As2 row stride (floats)

typedef float f32x2 __attribute__((ext_vector_type(2)));

__device__ __forceinline__ f32x2 pk_mul_lo(f32x2 a, f32x2 b) {
    f32x2 d;
    asm("v_pk_mul_f32 %0, %1, %2 op_sel:[0,0] op_sel_hi:[1,0]"
        : "=v"(d) : "v"(a), "v"(b));
    return d;
}
__device__ __forceinline__ f32x2 pk_mul_hi(f32x2 a, f32x2 b) {
    f32x2 d;
    asm("v_pk_mul_f32 %0, %1, %2 op_sel:[0,1] op_sel_hi:[1,1]"
        : "=v"(d) : "v"(a), "v"(b));
    return d;
}
__device__ __forceinline__ f32x2 pk_add(f32x2 a, f32x2 b) {
    f32x2 d;
    asm("v_pk_add_f32 %0, %1, %2" : "=v"(d) : "v"(a), "v"(b));
    return d;
}

// ---- kernel 0: pre-transform W into chunked, lane-linear slab image (as r6).
// Slab s = (e>>5)*2 + ((e>>4)&1), slot lane = (e&15)*4 + l.
// Bt[c][s*256 + lane*4 + q] = W[e][16c + 4q + l]
__global__ __launch_bounds__(256) void transform_kernel(
    const float* __restrict__ wgt, float* __restrict__ Bt)
{
    const int c    = blockIdx.x >> 2;
    const int qt   = blockIdx.x & 3;
    const int slot = qt * 256 + threadIdx.x;      // 0..1023
    const int s    = slot >> 6;                   // slab 0..15
    const int lane = slot & 63;
    const int em   = lane >> 2;
    const int l    = lane & 3;
    const int e    = (s >> 1) * 32 + (s & 1) * 16 + em;
    const float* src = wgt + (size_t)e * KD + 16 * c + l;
    float4 v = make_float4(src[0], src[4], src[8], src[12]);   // q = 0..3
    *(float4*)(Bt + (size_t)c * CHUNK_DW + slot * 4) = v;
}

typedef __attribute__((address_space(1))) const void GV;
typedef __attribute__((address_space(3))) void LV;
__device__ __forceinline__ void gld_lds16(const float* g, float* l) {
    __builtin_amdgcn_global_load_lds((GV*)g, (LV*)l, 16, 0, 0);
}

// Bit-exact numpy npyv(SSE3,no-FMA) einsum; lane-chains split across thread
// quads (l = tid&3); token-pairs packed in v_pk ops; BK=32 (two 16-blocks
// processed in ascending-k order per barrier phase).
__global__ __launch_bounds__(512, 4) void gate_kernel(
    const float* __restrict__ hid, const float* __restrict__ Bt,
    float* __restrict__ out, float* __restrict__ cnt, float* __restrict__ prb)
{
    __shared__ union { float bs[2][2 * CHUNK_DW]; float ls[TM][SL]; } sh;
    __shared__ float As2[2][4][SA];   // [buf][l][tp*16 + q*2 + par]
    __shared__ float maxS[TM], sumS[TM], invS[TM];

    const int tid  = threadIdx.x;
    const int l    = tid & 3;
    const int eg   = (tid >> 2) & 31;      // experts eg, eg+32, ..., eg+224
    const int tg   = tid >> 7;             // token group 0..3 (8 tokens each)
    const int t0   = blockIdx.x * TM;
    const int lane = tid & 63;
    const int w    = tid >> 6;
    const int h    = w & 1;                // expert half within slab pair

    f32x2 acc2[4][8];                      // [token-pair][j]
#pragma unroll
    for (int i = 0; i < 4; ++i)
#pragma unroll
        for (int j = 0; j < 8; ++j) acc2[i][j] = (f32x2){0.f, 0.f};

    // ---- A staging: 32 lanes/wave, at = token, aq = q-octet index 0..7 ----
    const bool aact = (lane < 32);
    const int  at   = w * 4 + (lane >> 3);   // token 0..31
    const int  aq   = lane & 7;              // q 0..7
    float av[4];                             // l = 0..3

    auto stageA_load = [&](int c) {          // c in BK=32 units
        if (aact)
            *(float4*)av = *(const float4*)(hid + (size_t)(t0 + at) * KD + 32 * c + 4 * aq);
    };
    auto stageA_write = [&](int buf) {
        if (aact) {
            const int base = (at >> 1) * 16 + aq * 2 + (at & 1);
#pragma unroll
            for (int ll = 0; ll < 4; ++ll)
                As2[buf][ll][base] = av[ll];
        }
    };
    auto stageB = [&](int c, int buf) {      // c in BK=32 units -> two 16-chunks
        const float* src = Bt + (size_t)(2 * c) * CHUNK_DW + tid * 4;
        float* dst = &sh.bs[buf][tid * 4];
#pragma unroll
        for (int s = 0; s < 4; ++s)
            gld_lds16(src + s * 2048, dst + s * 2048);
    };

    stageA_load(0);
    stageB(0, 0);
    stageA_write(0);
    int cur = 0;

#pragma unroll 1
    for (int c = 0; c < NCHUNK; ++c) {
        __syncthreads();                       // cur buffers ready; nxt free
        const int nxt = cur ^ 1;
        if (c + 1 < NCHUNK) { stageA_load(c + 1); stageB(c + 1, nxt); }

#pragma unroll
        for (int j16 = 0; j16 < 2; ++j16) {    // 16-blocks in ascending k
            float4 a0[4], a1[4];
#pragma unroll
            for (int tp = 0; tp < 4; ++tp) {
                const float* ap = &As2[cur][l][(tg * 4 + tp) * 16 + j16 * 8];
                a0[tp] = *(const float4*)(ap);       // {q0p0,q0p1,q1p0,q1p1}
                a1[tp] = *(const float4*)(ap + 4);   // {q2.., q3..}
            }
#pragma unroll
            for (int j = 0; j < 8; ++j) {
                const float4 b = *(const float4*)
                    &sh.bs[cur][j16 * CHUNK_DW + ((j * 2 + h) << 8) + (lane << 2)];
                const f32x2 b01 = (f32x2){b.x, b.y};   // {q0, q1}
                const f32x2 b23 = (f32x2){b.z, b.w};   // {q2, q3}
#pragma unroll
                for (int tp = 0; tp < 4; ++tp) {
                    const f32x2 aQ0 = (f32x2){a0[tp].x, a0[tp].y};
                    const f32x2 aQ1 = (f32x2){a0[tp].z, a0[tp].w};
                    const f32x2 aQ2 = (f32x2){a1[tp].x, a1[tp].y};
                    const f32x2 aQ3 = (f32x2){a1[tp].z, a1[tp].w};
                    f32x2 s = acc2[tp][j];
                    s = pk_add(pk_mul_hi(aQ3, b23), s);   // q=3
                    s = pk_add(pk_mul_lo(aQ2, b23), s);   // q=2
                    s = pk_add(pk_mul_hi(aQ1, b01), s);   // q=1
                    s = pk_add(pk_mul_lo(aQ0, b01), s);   // q=0
                    acc2[tp][j] = s;
                }
            }
        }
        if (c + 1 < NCHUNK) stageA_write(nxt);
        cur = nxt;
    }

    // ---- combine lane-chains: (s0+s1)+(s2+s3) per component ----
    __syncthreads();                           // all waves done reading bs
#pragma unroll
    for (int tp = 0; tp < 4; ++tp)
#pragma unroll
        for (int j = 0; j < 8; ++j) {
            float sx = acc2[tp][j].x, sy = acc2[tp][j].y;
            sx = __fadd_rn(sx, __shfl_xor(sx, 1));
            sx = __fadd_rn(sx, __shfl_xor(sx, 2));
            sy = __fadd_rn(sy, __shfl_xor(sy, 1));
            sy = __fadd_rn(sy, __shfl_xor(sy, 2));
            if (l == 0) {
                sh.ls[tg * 8 + 2 * tp][eg + 32 * j]     = sx;
                sh.ls[tg * 8 + 2 * tp + 1][eg + 32 * j] = sy;
            }
        }
    if (tid < TM) sumS[tid] = 0.f;
    __syncthreads();

    // ---- per-token top-k (threads 0..31), fp32 bit-exact ----
    if (tid < TM) {
        const float* lr = &sh.ls[tid][0];
        float tv[8]; int ti[8];
#pragma unroll
        for (int j = 0; j < 8; ++j) { tv[j] = -1e30f; ti[j] = 0; }
        float rowmax = -1e30f;

        auto ins8 = [&](float v, int idx) {
#pragma unroll
            for (int p = 0; p < 8; ++p) {
                if (v > tv[p]) {
#pragma unroll
                    for (int q = 7; q > p; --q) { tv[q] = tv[q - 1]; ti[q] = ti[q - 1]; }
                    tv[p] = v; ti[p] = idx;
                    break;
                }
            }
        };

#pragma unroll 1
        for (int g = 0; g < 8; ++g) {
            float v0 = -1e30f, v1 = -1e30f, v2 = -1e30f, v3 = -1e30f;
            int   i0 = 0, i1 = 0, i2 = 0, i3 = 0;
            for (int j = 0; j < 32; ++j) {
                const float v = lr[g * 32 + j];
                if (v > v0)      { v3=v2;i3=i2; v2=v1;i2=i1; v1=v0;i1=i0; v0=v;i0=j; }
                else if (v > v1) { v3=v2;i3=i2; v2=v1;i2=i1; v1=v;i1=j; }
                else if (v > v2) { v3=v2;i3=i2; v2=v;i2=j; }
                else if (v > v3) { v3=v;i3=j; }
            }
            rowmax = fmaxf(rowmax, v0);
            ins8(v0, g * 32 + i0);
            ins8(v1, g * 32 + i1);
            ins8(v2, g * 32 + i2);
            ins8(v3, g * 32 + i3);
        }

        const float s01 = __fadd_rn(tv[0], tv[1]);
        const float s23 = __fadd_rn(tv[2], tv[3]);
        const float s45 = __fadd_rn(tv[4], tv[5]);
        const float s67 = __fadd_rn(tv[6], tv[7]);
        float s = __fadd_rn(__fadd_rn(s01, s23), __fadd_rn(s45, s67));
        s = __fadd_rn(s, 1e-20f);

        const size_t tg2 = (size_t)(t0 + tid);
#pragma unroll
        for (int j = 0; j < 8; ++j) {
            out[tg2 * 8 + j]                    = (float)ti[j];
            out[(size_t)NTOK * 8 + tg2 * 8 + j] = __fdiv_rn(tv[j], s);
            atomicAdd(&cnt[ti[j]], 1.0f);
        }
        maxS[tid] = rowmax;
    }
    __syncthreads();

    // ---- per-token softmax denominator (16 threads per token, 32 tokens) ----
    {
        const int t  = tid >> 4;
        const int c0 = (tid & 15) * 16;
        const float m = maxS[t];
        float part = 0.f;
#pragma unroll
        for (int j = 0; j < 16; ++j) part += __expf(sh.ls[t][c0 + j] - m);
        atomicAdd(&sumS[t], part);
    }
    __syncthreads();
    if (tid < TM) invS[tid] = 1.0f / sumS[tid];
    __syncthreads();

    // ---- per-expert softmax-prob partial over block tokens ----
    if (tid < NE) {
        float p = 0.f;
#pragma unroll
        for (int n = 0; n < TM; ++n) p += __expf(sh.ls[n][tid] - maxS[n]) * invS[n];
        atomicAdd(&prb[tid], p);
    }
}

__global__ void aux_kernel(const float* __restrict__ cnt,
                           const float* __restrict__ prb,
                           float* __restrict__ out)
{
    const int tid = threadIdx.x;
    float v = cnt[tid] * prb[tid];
#pragma unroll
    for (int off = 32; off; off >>= 1) v += __shfl_down(v, off, 64);
    __shared__ float ps[4];
    if ((tid & 63) == 0) ps[tid >> 6] = v;
    __syncthreads();
    if (tid == 0) {
        const float tot = ps[0] + ps[1] + ps[2] + ps[3];
        out[(size_t)NTOK * 8 * 2] = tot * (0.001f / (131072.0f * 16384.0f));
    }
}

extern "C" void kernel_launch(void* const* d_in, const int* in_sizes, int n_in,
                              void* d_out, int out_size, void* d_ws, size_t ws_size,
                              hipStream_t stream)
{
    (void)in_sizes; (void)n_in; (void)out_size; (void)ws_size;
    const float* hid = (const float*)d_in[0];
    const float* wgt = (const float*)d_in[1];
    float* out = (float*)d_out;
    float* cnt = (float*)d_ws;             // 256 f
    float* prb = cnt + NE;                 // 256 f
    float* Bt  = prb + NE;                 // 2 MB image (16B-aligned offset)

    hipMemsetAsync(d_ws, 0, 2 * NE * sizeof(float), stream);
    transform_kernel<<<512, 256, 0, stream>>>(wgt, Bt);
    gate_kernel<<<NTOK / TM, 512, 0, stream>>>(hid, Bt, out, cnt, prb);
    aux_kernel<<<1, 256, 0, stream>>>(cnt, prb, out);
}